// Round 2
// baseline (1374.043 us; speedup 1.0000x reference)
//
#include <hip/hip_runtime.h>

typedef float f32x4 __attribute__((ext_vector_type(4)));
typedef __bf16 bf16x8 __attribute__((ext_vector_type(8)));
typedef unsigned short u16;
typedef unsigned int u32;

#define DEV static __device__ __forceinline__

DEV u16 f2b(float f) { union { float f; u32 u; } v; v.f = f; u32 r = v.u + 0x7fffu + ((v.u >> 16) & 1u); return (u16)(r >> 16); }
DEV float b2f(u16 h) { union { u32 u; float f; } v; v.u = ((u32)h) << 16; return v.f; }

DEV f32x4 mfma16(bf16x8 a, bf16x8 b, f32x4 c) {
    return __builtin_amdgcn_mfma_f32_16x16x32_bf16(a, b, c, 0, 0, 0);
}

// ---------------- bf16 tile helpers (MoE + final GEMM) ----------------
DEV void stageA_b16(const u16* A, int lda, int k0, u16 (*As)[72]) {
    int t = threadIdx.x, r = t >> 2, seg = (t & 3) * 16;
    const uint4* src = (const uint4*)(A + (size_t)r * lda + k0 + seg);
    uint4* dst = (uint4*)&As[r][seg];
    dst[0] = src[0]; dst[1] = src[1];
}
DEV void stageBT_f32(const float* W, int ldw, int k0, int n0, u16 (*Bs)[72]) {
    int t = threadIdx.x;
    int nq = (t & 15) * 4, kq = (t >> 4) * 4;
    float4 f[4];
#pragma unroll
    for (int j = 0; j < 4; ++j)
        f[j] = *(const float4*)(W + (size_t)(k0 + kq + j) * ldw + n0 + nq);
#pragma unroll
    for (int jj = 0; jj < 4; ++jj) {
        u16 a0 = f2b(((const float*)&f[0])[jj]);
        u16 a1 = f2b(((const float*)&f[1])[jj]);
        u16 a2 = f2b(((const float*)&f[2])[jj]);
        u16 a3 = f2b(((const float*)&f[3])[jj]);
        uint2 dv; dv.x = (u32)a0 | ((u32)a1 << 16); dv.y = (u32)a2 | ((u32)a3 << 16);
        *(uint2*)&Bs[nq + jj][kq] = dv;
    }
}
DEV void mfma_step(const u16 (*As)[72], const u16 (*Bs)[72], f32x4* acc, int w, int lr, int lg) {
#pragma unroll
    for (int kc = 0; kc < 2; ++kc) {
        bf16x8 b = *(const bf16x8*)&Bs[w*16 + lr][kc*32 + lg*8];
#pragma unroll
        for (int rb = 0; rb < 4; ++rb) {
            bf16x8 a = *(const bf16x8*)&As[rb*16 + lr][kc*32 + lg*8];
            acc[rb] = mfma16(a, b, acc[rb]);
        }
    }
}

// ---------------- prep: LN1 row stats of x (fp32) ----------------
__global__ __launch_bounds__(256) void k_prep(const float* __restrict__ x, float2* __restrict__ rstat0) {
    int row = blockIdx.x, t = threadIdx.x;
    float4 f = ((const float4*)(x + (size_t)row * 1024))[t];
    float s = f.x + f.y + f.z + f.w;
    float s2 = f.x*f.x + f.y*f.y + f.z*f.z + f.w*f.w;
#pragma unroll
    for (int d = 1; d < 64; d <<= 1) { s += __shfl_xor(s, d); s2 += __shfl_xor(s2, d); }
    __shared__ float red[8];
    int w = t >> 6;
    if ((t & 63) == 0) { red[w*2] = s; red[w*2+1] = s2; }
    __syncthreads();
    if (t == 0) {
        float S = red[0]+red[2]+red[4]+red[6], S2 = red[1]+red[3]+red[5]+red[7];
        float mean = S * (1.f/1024.f);
        float var = fmaxf((S2 - 1024.f*mean*mean) * (1.f/1023.f), 0.f);
        rstat0[row] = make_float2(mean, 1.f/(sqrtf(var)+1e-6f));
    }
}

// ---------------- fp32 small GEMM: M=64, K=1024, N=1024 (+optional RoPE) ----------------
struct SJob { const float* A; const float* W; float* out; int rope; };
struct SJobs { SJob j[6]; };

__global__ __launch_bounds__(256) void k_small32(SJobs jobs, const float* __restrict__ cosT,
                                                 const float* __restrict__ sinT) {
    __shared__ float At[16][72], Bt[16][72];
    SJob jb = jobs.j[blockIdx.y];
    int n0 = blockIdx.x * 64;
    int t = threadIdx.x, ty = t >> 4, tx = t & 15;
    int ar = t >> 2, ak = (t & 3) * 4;
    int bj = t >> 4, bn = (t & 15) * 4;
    float acc[4][4] = {};
    for (int k0 = 0; k0 < 1024; k0 += 16) {
        __syncthreads();
        float4 fa = *(const float4*)(jb.A + (size_t)ar * 1024 + k0 + ak);
        At[ak+0][ar] = fa.x; At[ak+1][ar] = fa.y; At[ak+2][ar] = fa.z; At[ak+3][ar] = fa.w;
        *(float4*)&Bt[bj][bn] = *(const float4*)(jb.W + (size_t)(k0 + bj) * 1024 + n0 + bn);
        __syncthreads();
#pragma unroll
        for (int kk = 0; kk < 16; ++kk) {
            float4 a4 = *(const float4*)&At[kk][ty*4];
            float4 b4 = *(const float4*)&Bt[kk][tx*4];
            float av[4] = {a4.x, a4.y, a4.z, a4.w};
            float bv[4] = {b4.x, b4.y, b4.z, b4.w};
#pragma unroll
            for (int i = 0; i < 4; ++i)
#pragma unroll
                for (int j = 0; j < 4; ++j)
                    acc[i][j] = fmaf(av[i], bv[j], acc[i][j]);
        }
    }
    if (jb.rope) {
#pragma unroll
        for (int i = 0; i < 4; ++i) {
            int row = ty*4 + i;
            float* orow = jb.out + (size_t)row*1024 + n0 + tx*4;
#pragma unroll
            for (int p = 0; p < 2; ++p) {
                int c = n0 + tx*4 + p*2;
                int fi = (c & 63) >> 1;
                float cs = cosT[row*32 + fi], sn = sinT[row*32 + fi];
                float e1 = acc[i][p*2], e2 = acc[i][p*2+1];
                orow[p*2]   = e1*cs - e2*sn;
                orow[p*2+1] = e1*sn + e2*cs;
            }
        }
    } else {
#pragma unroll
        for (int i = 0; i < 4; ++i) {
            float4 o = {acc[i][0], acc[i][1], acc[i][2], acc[i][3]};
            *(float4*)(jb.out + (size_t)(ty*4 + i)*1024 + n0 + tx*4) = o;
        }
    }
}

// ---------------- fp32 small attention (64 q x 64 k per head) ----------------
__global__ __launch_bounds__(256) void k_attn_small(const float* __restrict__ Q, long qbs,
                                                    const float* __restrict__ K, const float* __restrict__ V,
                                                    float* __restrict__ z, int causal) {
    __shared__ float Qs[64][65], Ks[64][65], Vs[64][65], Ss[64][65];
    int h = blockIdx.x, b = blockIdx.y;
    const float* Qb = Q + (size_t)b * qbs;
    const float* Kb = K + (size_t)b * 65536;
    const float* Vb = V + (size_t)b * 65536;
    int t = threadIdx.x, r = t >> 2, seg = (t & 3) * 16;
#pragma unroll
    for (int j = 0; j < 16; ++j) {
        Qs[r][seg+j] = Qb[(size_t)r*1024 + h*64 + seg + j];
        Ks[r][seg+j] = Kb[(size_t)r*1024 + h*64 + seg + j];
        Vs[r][seg+j] = Vb[(size_t)r*1024 + h*64 + seg + j];
    }
    __syncthreads();
    float sv[16];
    for (int j = 0; j < 16; ++j) {
        int k = seg + j;
        float acc = 0.f;
        for (int d = 0; d < 64; ++d) acc += Qs[r][d] * Ks[k][d];
        sv[j] = acc * 0.125f;
    }
    __syncthreads();
#pragma unroll
    for (int j = 0; j < 16; ++j) Ss[r][seg+j] = sv[j];
    __syncthreads();
    if (t < 64) {
        int lim = causal ? (t + 1) : 64;
        float mm = -1e30f;
        for (int k2 = 0; k2 < lim; ++k2) mm = fmaxf(mm, Ss[t][k2]);
        float ssum = 0.f;
        for (int k2 = 0; k2 < lim; ++k2) { float pv = __expf(Ss[t][k2] - mm); Ss[t][k2] = pv; ssum += pv; }
        float inv = 1.f / ssum;
        for (int k2 = 0; k2 < lim; ++k2) Ss[t][k2] *= inv;
        for (int k2 = lim; k2 < 64; ++k2) Ss[t][k2] = 0.f;
    }
    __syncthreads();
    for (int j = 0; j < 16; ++j) {
        int d0 = seg + j;
        float acc = 0.f;
        for (int k2 = 0; k2 < 64; ++k2) acc += Ss[r][k2] * Vs[k2][d0];
        z[(size_t)b*65536 + (size_t)r*1024 + h*64 + d0] = acc;
    }
}

// ---------------- fp32 big GEMM: M=4096, K=1024, N=1024; tile 256x64, thread 16x4 ----------------
// MODE 0: RoPE epilogue -> outf (qx). MODE 1: + LN1(xref) -> outf (x1f) and outb (x1b bf16).
template<int MODE>
__global__ __launch_bounds__(256) void k_gemm32_big(
    const float* __restrict__ A, const float* __restrict__ W,
    float* __restrict__ outf, u16* __restrict__ outb,
    const float* __restrict__ xref, const float2* __restrict__ rstat,
    const float* __restrict__ g, const float* __restrict__ beta,
    const float* __restrict__ cosT, const float* __restrict__ sinT)
{
    __shared__ float At[16][264];
    __shared__ float Bt[16][72];
    int n0 = blockIdx.x * 64, m0 = blockIdx.y * 256;
    int t = threadIdx.x, ty = t >> 4, tx = t & 15;
    int bj = t >> 4, bn = (t & 15) * 4;
    float acc[16][4] = {};
    for (int k0 = 0; k0 < 1024; k0 += 16) {
        __syncthreads();
        const float* arow = A + (size_t)(m0 + t) * 1024 + k0;
#pragma unroll
        for (int q = 0; q < 4; ++q) {
            float4 fa = *(const float4*)(arow + q*4);
            At[q*4+0][t] = fa.x; At[q*4+1][t] = fa.y; At[q*4+2][t] = fa.z; At[q*4+3][t] = fa.w;
        }
        *(float4*)&Bt[bj][bn] = *(const float4*)(W + (size_t)(k0 + bj) * 1024 + n0 + bn);
        __syncthreads();
#pragma unroll
        for (int kk = 0; kk < 16; ++kk) {
            float4 b4 = *(const float4*)&Bt[kk][tx*4];
            float bv[4] = {b4.x, b4.y, b4.z, b4.w};
#pragma unroll
            for (int q = 0; q < 4; ++q) {
                float4 a4 = *(const float4*)&At[kk][ty*16 + q*4];
                float av[4] = {a4.x, a4.y, a4.z, a4.w};
#pragma unroll
                for (int i = 0; i < 4; ++i)
#pragma unroll
                    for (int j = 0; j < 4; ++j)
                        acc[q*4+i][j] = fmaf(av[i], bv[j], acc[q*4+i][j]);
            }
        }
    }
    if constexpr (MODE == 0) {
#pragma unroll
        for (int i = 0; i < 16; ++i) {
            int row = m0 + ty*16 + i, pos = row & 2047;
            float* orow = outf + (size_t)row*1024 + n0 + tx*4;
#pragma unroll
            for (int p = 0; p < 2; ++p) {
                int c = n0 + tx*4 + p*2;
                int fi = (c & 63) >> 1;
                float cs = cosT[pos*32 + fi], sn = sinT[pos*32 + fi];
                float e1 = acc[i][p*2], e2 = acc[i][p*2+1];
                orow[p*2]   = e1*cs - e2*sn;
                orow[p*2+1] = e1*sn + e2*cs;
            }
        }
    } else {
        int cb = n0 + tx*4;
        float4 g4 = *(const float4*)(g + cb);
        float4 be4 = *(const float4*)(beta + cb);
        float gv[4] = {g4.x, g4.y, g4.z, g4.w};
        float bb[4] = {be4.x, be4.y, be4.z, be4.w};
#pragma unroll
        for (int i = 0; i < 16; ++i) {
            int row = m0 + ty*16 + i;
            float2 st = rstat[row];
            float4 xr = *(const float4*)(xref + (size_t)row*1024 + cb);
            float xv[4] = {xr.x, xr.y, xr.z, xr.w};
            float vo[4];
#pragma unroll
            for (int j = 0; j < 4; ++j) {
                float val = acc[i][j] + gv[j]*(xv[j]-st.x)*st.y + bb[j];
                vo[j] = val;
                outb[(size_t)row*1024 + cb + j] = f2b(val);
            }
            float4 ov = {vo[0], vo[1], vo[2], vo[3]};
            *(float4*)(outf + (size_t)row*1024 + cb) = ov;
        }
    }
}

// ---------------- fp32 attention stage 3: 2048 q x 64 k per (b,h) ----------------
__global__ __launch_bounds__(256) void k_attn3_f32(const float* __restrict__ qx, const float* __restrict__ kz,
                                                   const float* __restrict__ vz, float* __restrict__ xl) {
    __shared__ float Qt[64][72], Kt[64][72], Vs[64][72], Pt[64][72];
    int qt = blockIdx.x, h = blockIdx.y, b = blockIdx.z;
    const float* Qb = qx + (size_t)(b*2048 + qt*64) * 1024 + h*64;
    const float* Kb = kz + (size_t)b*65536 + h*64;
    const float* Vb = vz + (size_t)b*65536 + h*64;
    int t = threadIdx.x, r = t >> 2, sg = (t & 3) * 16;
#pragma unroll
    for (int j = 0; j < 16; ++j) {
        Qt[sg+j][r] = Qb[(size_t)r*1024 + sg + j];
        Kt[sg+j][r] = Kb[(size_t)r*1024 + sg + j];
        Vs[r][sg+j] = Vb[(size_t)r*1024 + sg + j];
    }
    __syncthreads();
    int ty = t >> 4, tx = t & 15;
    float acc[4][4] = {};
    for (int d = 0; d < 64; ++d) {
        float4 a4 = *(const float4*)&Qt[d][ty*4];
        float4 b4 = *(const float4*)&Kt[d][tx*4];
        float av[4] = {a4.x, a4.y, a4.z, a4.w};
        float bv[4] = {b4.x, b4.y, b4.z, b4.w};
#pragma unroll
        for (int i = 0; i < 4; ++i)
#pragma unroll
            for (int j = 0; j < 4; ++j)
                acc[i][j] = fmaf(av[i], bv[j], acc[i][j]);
    }
#pragma unroll
    for (int i = 0; i < 4; ++i)
#pragma unroll
        for (int j = 0; j < 4; ++j)
            Pt[tx*4+j][ty*4+i] = acc[i][j] * 0.125f;
    __syncthreads();
    if (t < 64) {
        float mm = -1e30f;
        for (int k = 0; k < 64; ++k) mm = fmaxf(mm, Pt[k][t]);
        float ss = 0.f;
        for (int k = 0; k < 64; ++k) { float p = __expf(Pt[k][t] - mm); Pt[k][t] = p; ss += p; }
        float inv = 1.f / ss;
        for (int k = 0; k < 64; ++k) Pt[k][t] *= inv;
    }
    __syncthreads();
    float oac[4][4] = {};
    for (int k = 0; k < 64; ++k) {
        float4 a4 = *(const float4*)&Pt[k][ty*4];
        float4 b4 = *(const float4*)&Vs[k][tx*4];
        float av[4] = {a4.x, a4.y, a4.z, a4.w};
        float bv[4] = {b4.x, b4.y, b4.z, b4.w};
#pragma unroll
        for (int i = 0; i < 4; ++i)
#pragma unroll
            for (int j = 0; j < 4; ++j)
                oac[i][j] = fmaf(av[i], bv[j], oac[i][j]);
    }
#pragma unroll
    for (int i = 0; i < 4; ++i) {
        float4 o = {oac[i][0], oac[i][1], oac[i][2], oac[i][3]};
        *(float4*)(xl + (size_t)(b*2048 + qt*64 + ty*4 + i)*1024 + h*64 + tx*4) = o;
    }
}

// ---------------- router (fp32 x1): logits, top-2, bucket scatter, LN2 stats ----------------
__global__ __launch_bounds__(256) void k_router(const float* __restrict__ x1f, const float* __restrict__ rw,
                                                const float* __restrict__ rbias, float* __restrict__ probs,
                                                int* __restrict__ cnt, int* __restrict__ pidx,
                                                int* __restrict__ pkk, float2* __restrict__ rstat1) {
    int t = threadIdx.x, w = t >> 6, l = t & 63;
    int n = blockIdx.x * 4 + w;
    const float* xr = x1f + (size_t)n * 1024 + l*16;
    float xs[16];
#pragma unroll
    for (int q = 0; q < 4; ++q) *(float4*)&xs[q*4] = *(const float4*)(xr + q*4);
    float acc[8] = {0,0,0,0,0,0,0,0};
    float s = 0.f, s2 = 0.f;
#pragma unroll
    for (int j = 0; j < 16; ++j) {
        float xv = xs[j];
        s += xv; s2 += xv*xv;
        const float* wr = rw + (size_t)(l*16 + j) * 8;
        float4 w0 = *(const float4*)wr;
        float4 w1 = *(const float4*)(wr + 4);
        acc[0] += xv*w0.x; acc[1] += xv*w0.y; acc[2] += xv*w0.z; acc[3] += xv*w0.w;
        acc[4] += xv*w1.x; acc[5] += xv*w1.y; acc[6] += xv*w1.z; acc[7] += xv*w1.w;
    }
#pragma unroll
    for (int d = 1; d < 64; d <<= 1) {
#pragma unroll
        for (int e = 0; e < 8; ++e) acc[e] += __shfl_xor(acc[e], d);
        s += __shfl_xor(s, d); s2 += __shfl_xor(s2, d);
    }
    if (l == 0) {
        float mean = s * (1.f/1024.f);
        float var = fmaxf((s2 - 1024.f*mean*mean) * (1.f/1023.f), 0.f);
        rstat1[n] = make_float2(mean, 1.f/(sqrtf(var)+1e-6f));
        float lgt[8];
#pragma unroll
        for (int e = 0; e < 8; ++e) lgt[e] = acc[e] + rbias[e];
        int i0 = 0; float v0 = lgt[0];
#pragma unroll
        for (int e = 1; e < 8; ++e) if (lgt[e] > v0) { v0 = lgt[e]; i0 = e; }
        int i1 = -1; float v1 = -1e30f;
#pragma unroll
        for (int e = 0; e < 8; ++e) if (e != i0 && lgt[e] > v1) { v1 = lgt[e]; i1 = e; }
        float e1 = __expf(v1 - v0);
        float inv = 1.f / (1.f + e1);
        probs[n*2+0] = inv; probs[n*2+1] = e1 * inv;
        int s0 = atomicAdd(&cnt[i0], 1);
        pidx[i0*4096 + s0] = n; pkk[i0*4096 + s0] = 0;
        int s1 = atomicAdd(&cnt[i1], 1);
        pidx[i1*4096 + s1] = n; pkk[i1*4096 + s1] = 1;
    }
}

__global__ void k_scan(const int* __restrict__ cnt, int* __restrict__ off8) {
    if (threadIdx.x == 0) {
        int s = 0;
        for (int e = 0; e < 8; ++e) { off8[e] = s; s += cnt[e]; }
    }
}

// ---------------- MoE up-proj (bf16 MFMA): hsw = (x1 We_w) * silu(x1 We_v) ----------------
__global__ __launch_bounds__(256) void k_moe1(const u16* __restrict__ x1b, const float* __restrict__ Wew,
                                              const float* __restrict__ Wev, const int* __restrict__ cnt,
                                              const int* __restrict__ off8, const int* __restrict__ pidx,
                                              u16* __restrict__ hbuf) {
    int e = blockIdx.z, n0 = blockIdx.x * 64, r0 = blockIdx.y * 64;
    int ce = cnt[e];
    if (r0 >= ce) return;
    __shared__ u16 As[64][72], Bw[64][72], Bv[64][72];
    __shared__ int toks[64];
    int t = threadIdx.x, w = t >> 6, l = t & 63, lr = l & 15, lg = l >> 4;
    if (t < 64) toks[t] = pidx[e*4096 + ((r0 + t < ce) ? (r0 + t) : r0)];
    const float* Ww = Wew + (size_t)e * 1024 * 2048;
    const float* Wv = Wev + (size_t)e * 1024 * 2048;
    f32x4 zed = {0.f, 0.f, 0.f, 0.f};
    f32x4 acca[4], accb[4];
    acca[0]=zed; acca[1]=zed; acca[2]=zed; acca[3]=zed;
    accb[0]=zed; accb[1]=zed; accb[2]=zed; accb[3]=zed;
    int r = t >> 2, seg = (t & 3) * 16;
    for (int k0 = 0; k0 < 1024; k0 += 64) {
        __syncthreads();
        {
            const uint4* src = (const uint4*)(x1b + (size_t)toks[r]*1024 + k0 + seg);
            uint4* dst = (uint4*)&As[r][seg];
            dst[0] = src[0]; dst[1] = src[1];
        }
        stageBT_f32(Ww, 2048, k0, n0, Bw);
        stageBT_f32(Wv, 2048, k0, n0, Bv);
        __syncthreads();
#pragma unroll
        for (int kc = 0; kc < 2; ++kc) {
            bf16x8 bw = *(const bf16x8*)&Bw[w*16 + lr][kc*32 + lg*8];
            bf16x8 bv2 = *(const bf16x8*)&Bv[w*16 + lr][kc*32 + lg*8];
#pragma unroll
            for (int rb = 0; rb < 4; ++rb) {
                bf16x8 a = *(const bf16x8*)&As[rb*16 + lr][kc*32 + lg*8];
                acca[rb] = mfma16(a, bw, acca[rb]);
                accb[rb] = mfma16(a, bv2, accb[rb]);
            }
        }
    }
    int gbase = off8[e] + r0;
    int col = n0 + w*16 + lr;
#pragma unroll
    for (int rb = 0; rb < 4; ++rb)
#pragma unroll
        for (int rr = 0; rr < 4; ++rr) {
            int rl = rb*16 + lg*4 + rr;
            if (r0 + rl < ce) {
                float av = acca[rb][rr], bb = accb[rb][rr];
                float hv = av * bb / (1.f + __expf(-bb));
                hbuf[(size_t)(gbase + rl)*2048 + col] = f2b(hv);
            }
        }
}

// ---------------- MoE down-proj (bf16 MFMA): ypair = prob * (hsw We_o) ----------------
__global__ __launch_bounds__(256) void k_moe2(const u16* __restrict__ hbuf, const float* __restrict__ Weo,
                                              const int* __restrict__ cnt, const int* __restrict__ off8,
                                              const int* __restrict__ pidx, const int* __restrict__ pkk,
                                              const float* __restrict__ probs, u16* __restrict__ ypair) {
    int e = blockIdx.z, n0 = blockIdx.x * 64, r0 = blockIdx.y * 64;
    int ce = cnt[e];
    if (r0 >= ce) return;
    __shared__ u16 As[64][72], Bs[64][72];
    __shared__ int tn[64]; __shared__ int tk[64]; __shared__ float tp[64];
    int t = threadIdx.x, w = t >> 6, l = t & 63, lr = l & 15, lg = l >> 4;
    if (t < 64) {
        int slot = (r0 + t < ce) ? (r0 + t) : r0;
        int n = pidx[e*4096 + slot], k = pkk[e*4096 + slot];
        tn[t] = n; tk[t] = k; tp[t] = probs[n*2 + k];
    }
    const u16* Ab = hbuf + (size_t)(off8[e] + r0) * 2048;
    const float* Wo = Weo + (size_t)e * 2048 * 1024;
    f32x4 zed = {0.f, 0.f, 0.f, 0.f};
    f32x4 acc[4]; acc[0]=zed; acc[1]=zed; acc[2]=zed; acc[3]=zed;
    for (int k0 = 0; k0 < 2048; k0 += 64) {
        __syncthreads();
        stageA_b16(Ab, 2048, k0, As);
        stageBT_f32(Wo, 1024, k0, n0, Bs);
        __syncthreads();
        mfma_step(As, Bs, acc, w, lr, lg);
    }
    int col = n0 + w*16 + lr;
#pragma unroll
    for (int rb = 0; rb < 4; ++rb)
#pragma unroll
        for (int rr = 0; rr < 4; ++rr) {
            int rl = rb*16 + lg*4 + rr;
            if (r0 + rl < ce) {
                float val = acc[rb][rr] * tp[rl];
                ypair[((size_t)tn[rl]*2 + tk[rl])*1024 + col] = f2b(val);
            }
        }
}

// ---------------- finalize: x2 = LN2(x1) + moe, LN3 row stats ----------------
__global__ __launch_bounds__(256) void k_finalize(const float* __restrict__ x1f, const float2* __restrict__ rstat1,
                                                  const float* __restrict__ g2, const float* __restrict__ b2v,
                                                  const u16* __restrict__ ypair, u16* __restrict__ x2b,
                                                  float2* __restrict__ rstat2) {
    int n = blockIdx.x, t = threadIdx.x;
    float2 st = rstat1[n];
    const float* x1r = x1f + (size_t)n * 1024;
    const u16* y0 = ypair + (size_t)(n*2 + 0) * 1024;
    const u16* y1 = ypair + (size_t)(n*2 + 1) * 1024;
    float4 xv = *(const float4*)(x1r + t*4);
    float xa[4] = {xv.x, xv.y, xv.z, xv.w};
    float vals[4];
    float s = 0.f, s2 = 0.f;
#pragma unroll
    for (int j = 0; j < 4; ++j) {
        int c = t*4 + j;
        float v = g2[c] * (xa[j] - st.x) * st.y + b2v[c] + b2f(y0[c]) + b2f(y1[c]);
        vals[j] = v; s += v; s2 += v*v;
    }
#pragma unroll
    for (int d = 1; d < 64; d <<= 1) { s += __shfl_xor(s, d); s2 += __shfl_xor(s2, d); }
    __shared__ float red[8];
    int w = t >> 6;
    if ((t & 63) == 0) { red[w*2] = s; red[w*2+1] = s2; }
    __syncthreads();
    if (t == 0) {
        float S = red[0]+red[2]+red[4]+red[6], S2 = red[1]+red[3]+red[5]+red[7];
        float mean = S * (1.f/1024.f);
        float var = fmaxf((S2 - 1024.f*mean*mean) * (1.f/1023.f), 0.f);
        rstat2[n] = make_float2(mean, 1.f/(sqrtf(var)+1e-6f));
    }
    u32 p0 = (u32)f2b(vals[0]) | ((u32)f2b(vals[1]) << 16);
    u32 p1 = (u32)f2b(vals[2]) | ((u32)f2b(vals[3]) << 16);
    *(uint2*)(x2b + (size_t)n*1024 + t*4) = make_uint2(p0, p1);
}

// ---------------- final GEMM (bf16): out = LN3(x2) + x2 @ lin_w + lin_b ----------------
__global__ __launch_bounds__(256) void k_final_gemm(
    const u16* __restrict__ A, const float* __restrict__ W, float* __restrict__ out,
    const u16* __restrict__ xref, const float2* __restrict__ rstat,
    const float* __restrict__ g, const float* __restrict__ bta, const float* __restrict__ bias) {
    __shared__ u16 As[64][72], Bs[64][72];
    int n0 = blockIdx.x * 64, m0 = blockIdx.y * 64;
    int t = threadIdx.x, w = t >> 6, l = t & 63, lr = l & 15, lg = l >> 4;
    f32x4 zed = {0.f, 0.f, 0.f, 0.f};
    f32x4 acc[4]; acc[0]=zed; acc[1]=zed; acc[2]=zed; acc[3]=zed;
    for (int k0 = 0; k0 < 1024; k0 += 64) {
        __syncthreads();
        stageA_b16(A + (size_t)m0 * 1024, 1024, k0, As);
        stageBT_f32(W, 1024, k0, n0, Bs);
        __syncthreads();
        mfma_step(As, Bs, acc, w, lr, lg);
    }
    int col = n0 + w*16 + lr;
    float gv = g[col], bv = bta[col], biasv = bias[col];
#pragma unroll
    for (int rb = 0; rb < 4; ++rb)
#pragma unroll
        for (int rr = 0; rr < 4; ++rr) {
            int row = m0 + rb*16 + lg*4 + rr;
            float2 st = rstat[row];
            out[(size_t)row*1024 + col] = acc[rb][rr] + gv * (b2f(xref[(size_t)row*1024 + col]) - st.x) * st.y + bv + biasv;
        }
}

extern "C" void kernel_launch(void* const* d_in, const int* in_sizes, int n_in,
                              void* d_out, int out_size, void* d_ws, size_t ws_size,
                              hipStream_t stream) {
    (void)in_sizes; (void)n_in; (void)out_size; (void)ws_size;
    const float* x      = (const float*)d_in[0];
    const float* cosT   = (const float*)d_in[1];
    const float* sinT   = (const float*)d_in[2];
    const float* ln1g   = (const float*)d_in[3];
    const float* ln1b   = (const float*)d_in[4];
    const float* ln2g   = (const float*)d_in[5];
    const float* ln2b   = (const float*)d_in[6];
    const float* ln3g   = (const float*)d_in[7];
    const float* ln3b   = (const float*)d_in[8];
    const float* Lat    = (const float*)d_in[9];
    const float* wq_lat = (const float*)d_in[10];
    const float* wk_in  = (const float*)d_in[11];
    const float* wv_in  = (const float*)d_in[12];
    const float* wq_in  = (const float*)d_in[13];
    const float* wk_lat = (const float*)d_in[14];
    const float* wv_lat = (const float*)d_in[15];
    const float* w_out  = (const float*)d_in[16];
    const float* rw     = (const float*)d_in[17];
    const float* rbias  = (const float*)d_in[18];
    const float* We_w   = (const float*)d_in[19];
    const float* We_v   = (const float*)d_in[20];
    const float* We_o   = (const float*)d_in[21];
    const float* lin_w  = (const float*)d_in[22];
    const float* lin_b  = (const float*)d_in[23];

    char* p = (char*)d_ws;
    auto alloc = [&](size_t b) { char* r = p; p += (b + 255) & ~(size_t)255; return r; };
    float*  qx     = (float*) alloc(4096ull*1024*4);   // also reused as x1f
    float*  xlf    = (float*) alloc(4096ull*1024*4);   // also reused as ypair (bf16)
    u16*    x1b    = (u16*)   alloc(4096ull*1024*2);
    u16*    x2b    = (u16*)   alloc(4096ull*1024*2);
    u16*    hbuf   = (u16*)   alloc(8192ull*2048*2);
    float*  qlat   = (float*) alloc(64ull*1024*4);
    float*  k1     = (float*) alloc(2ull*64*1024*4);
    float*  v1     = (float*) alloc(2ull*64*1024*4);
    float*  zb     = (float*) alloc(2ull*64*1024*4);
    float*  ql     = (float*) alloc(2ull*64*1024*4);
    float*  kl     = (float*) alloc(2ull*64*1024*4);
    float*  vl     = (float*) alloc(2ull*64*1024*4);
    float*  z2b    = (float*) alloc(2ull*64*1024*4);
    float*  kz     = (float*) alloc(2ull*64*1024*4);
    float*  vz     = (float*) alloc(2ull*64*1024*4);
    float2* rstat0 = (float2*)alloc(4096ull*8);
    float2* rstat1 = (float2*)alloc(4096ull*8);
    float2* rstat2 = (float2*)alloc(4096ull*8);
    float*  probs  = (float*) alloc(4096ull*2*4);
    int*    cnt    = (int*)   alloc(8*4);
    int*    off8   = (int*)   alloc(8*4);
    int*    pidx   = (int*)   alloc(8ull*4096*4);
    int*    pkk    = (int*)   alloc(8ull*4096*4);
    float*  x1f    = qx;            // alias: qx dead after attn3
    u16*    ypair  = (u16*)xlf;     // alias: xlf dead after x1 GEMM

    k_prep<<<4096, 256, 0, stream>>>(x, rstat0);

    SJobs ja;
    ja.j[0] = SJob{Lat,           wq_lat, qlat,       0};
    ja.j[1] = SJob{x,             wk_in,  k1,         1};
    ja.j[2] = SJob{x + 2048*1024, wk_in,  k1 + 65536, 1};
    ja.j[3] = SJob{x,             wv_in,  v1,         0};
    ja.j[4] = SJob{x + 2048*1024, wv_in,  v1 + 65536, 0};
    ja.j[5] = SJob{nullptr, nullptr, nullptr, 0};
    k_small32<<<dim3(16,5), 256, 0, stream>>>(ja, cosT, sinT);

    k_attn_small<<<dim3(16,2), 256, 0, stream>>>(qlat, 0L, k1, v1, zb, 1);

    SJobs jb2;
    jb2.j[0] = SJob{zb,         wq_lat, ql,         0};
    jb2.j[1] = SJob{zb + 65536, wq_lat, ql + 65536, 0};
    jb2.j[2] = SJob{zb,         wk_lat, kl,         0};
    jb2.j[3] = SJob{zb + 65536, wk_lat, kl + 65536, 0};
    jb2.j[4] = SJob{zb,         wv_lat, vl,         0};
    jb2.j[5] = SJob{zb + 65536, wv_lat, vl + 65536, 0};
    k_small32<<<dim3(16,6), 256, 0, stream>>>(jb2, cosT, sinT);

    k_attn_small<<<dim3(16,2), 256, 0, stream>>>(ql, 65536L, kl, vl, z2b, 0);

    SJobs jc;
    jc.j[0] = SJob{z2b,         wk_lat, kz,         0};
    jc.j[1] = SJob{z2b + 65536, wk_lat, kz + 65536, 0};
    jc.j[2] = SJob{z2b,         wv_lat, vz,         0};
    jc.j[3] = SJob{z2b + 65536, wv_lat, vz + 65536, 0};
    jc.j[4] = SJob{nullptr, nullptr, nullptr, 0};
    jc.j[5] = SJob{nullptr, nullptr, nullptr, 0};
    k_small32<<<dim3(16,4), 256, 0, stream>>>(jc, cosT, sinT);

    k_gemm32_big<0><<<dim3(16,16), 256, 0, stream>>>(x, wq_in, qx, nullptr, nullptr, nullptr,
                                                     nullptr, nullptr, cosT, sinT);

    k_attn3_f32<<<dim3(32,16,2), 256, 0, stream>>>(qx, kz, vz, xlf);

    k_gemm32_big<1><<<dim3(16,16), 256, 0, stream>>>(xlf, w_out, x1f, x1b, x, rstat0,
                                                     ln1g, ln1b, nullptr, nullptr);

    hipMemsetAsync(cnt, 0, 8*sizeof(int), stream);
    k_router<<<1024, 256, 0, stream>>>(x1f, rw, rbias, probs, cnt, pidx, pkk, rstat1);
    k_scan<<<1, 64, 0, stream>>>(cnt, off8);

    k_moe1<<<dim3(32,64,8), 256, 0, stream>>>(x1b, We_w, We_v, cnt, off8, pidx, hbuf);
    k_moe2<<<dim3(16,64,8), 256, 0, stream>>>(hbuf, We_o, cnt, off8, pidx, pkk, probs, ypair);

    k_finalize<<<4096, 256, 0, stream>>>(x1f, rstat1, ln2g, ln2b, ypair, x2b, rstat2);

    k_final_gemm<<<dim3(16,64), 256, 0, stream>>>(x2b, lin_w, (float*)d_out, x2b, rstat2,
                                                  ln3g, ln3b, lin_b);
}